// Round 5
// baseline (210.614 us; speedup 1.0000x reference)
//
#include <hip/hip_runtime.h>

#define WDIM 1920
#define HDIM 1080
#define TPB 256
#define PPB 4                 // pairs per block
#define NBLK 2048             // 8192 / PPB
#define XF4 (PPB * WDIM / 4)  // 1920 float4s per block x-region
#define YF4 (PPB * HDIM / 4)  // 1080 float4s per block y-region
#define LN2 0.69314718056f

__device__ __forceinline__ float clog1m(float p) {
    return fmaxf(__log2f(1.f - p) * LN2, -100.f);
}
__device__ __forceinline__ float clogp(float p) {
    return fmaxf(__log2f(p) * LN2, -100.f);
}

// ws layout: pl[NBLK] | pc[NBLK] | ticket (uint)
__global__ __launch_bounds__(TPB) void bce_fused(const float* __restrict__ px,
                                                 const float* __restrict__ py,
                                                 const int2* __restrict__ tgt,
                                                 float* __restrict__ pl,
                                                 float* __restrict__ pc,
                                                 unsigned* __restrict__ ticket,
                                                 float* __restrict__ out) {
    const int t = threadIdx.x;
    const int blk = blockIdx.x;
    const int p0 = blk * PPB;

    // Per-pair stream weights (vm * -ln2/L); block owns its 4 pairs.
    __shared__ float wx[PPB], wy[PPB];
    int cx = 0, cy = 0;
    float vm = 0.f;
    if (t < PPB) {
        int2 t2 = tgt[p0 + t];
        cx = min(max(t2.x, 0), WDIM - 1);
        cy = min(max(t2.y, 0), HDIM - 1);
        vm = (cx == 0 && cy == 0) ? 0.f : 1.f;
        wx[t] = vm * (-LN2 / WDIM);
        wy[t] = vm * (-LN2 / HDIM);
    }
    __syncthreads();

    float acc = 0.f, cnt = 0.f;
    // Target-element corrections: owning block, one pair per lane (t<4).
    // p can be 0/1 here -> keep clamps.
    if (t < PPB && vm != 0.f) {
        float pt = px[(size_t)(p0 + t) * WDIM + cx];
        float qt = py[(size_t)(p0 + t) * HDIM + cy];
        acc += (clog1m(pt) - clogp(pt)) * (1.f / WDIM)
             + (clog1m(qt) - clogp(qt)) * (1.f / HDIM);
        cnt = 1.f;
    }

    const float4* bx = (const float4*)px + (size_t)blk * XF4;
    const float4* by = (const float4*)py + (size_t)blk * YF4;
    const float4 z4 = make_float4(0.f, 0.f, 0.f, 0.f);

    // ---- x region: 1920 float4s, batched loads, predicated tail ----
    float4 vx[8];
    #pragma unroll
    for (int j = 0; j < 8; ++j) {
        int idx = t + j * TPB;
        vx[j] = (j < 7 || t < XF4 - 7 * TPB) ? bx[idx] : z4;   // pad -> q=1 -> log 0
    }
    #pragma unroll
    for (int j = 0; j < 8; ++j) {
        int idx = t + j * TPB;
        int pli = idx / 480;
        float4 v = vx[j];
        // log-of-product-of-4: min (5.96e-8)^4 = 1.26e-29 (normal); per-element
        // log >= -16.6 so the -100 clamp can never bind on this path.
        float q = (1.f - v.x) * (1.f - v.y) * (1.f - v.z) * (1.f - v.w);
        acc += wx[pli] * __log2f(q);
    }

    // ---- y region: 1080 float4s ----
    float4 vy[5];
    #pragma unroll
    for (int j = 0; j < 5; ++j) {
        int idx = t + j * TPB;
        vy[j] = (j < 4 || t < YF4 - 4 * TPB) ? by[idx] : z4;
    }
    #pragma unroll
    for (int j = 0; j < 5; ++j) {
        int idx = t + j * TPB;
        int pli = idx / 270;
        float4 v = vy[j];
        float q = (1.f - v.x) * (1.f - v.y) * (1.f - v.z) * (1.f - v.w);
        acc += wy[pli] * __log2f(q);
    }

    // block reduce
    #pragma unroll
    for (int o = 32; o > 0; o >>= 1) {
        acc += __shfl_down(acc, o, 64);
        cnt += __shfl_down(cnt, o, 64);
    }
    __shared__ float rs[TPB / 64], rc[TPB / 64];
    if ((t & 63) == 0) { rs[t >> 6] = acc; rc[t >> 6] = cnt; }
    __syncthreads();

    // last-block-done final reduction (one device atomic per block)
    __shared__ int amLast;
    if (t == 0) {
        pl[blk] = rs[0] + rs[1] + rs[2] + rs[3];
        pc[blk] = rc[0] + rc[1] + rc[2] + rc[3];
        __threadfence();                       // publish partials device-wide
        unsigned prev = atomicAdd(ticket, 1u); // device-scope RMW
        amLast = (prev == NBLK - 1) ? 1 : 0;
    }
    __syncthreads();

    if (amLast) {
        __threadfence();                       // acquire side
        float s = 0.f, c = 0.f;
        for (int i = t; i < NBLK; i += TPB) {
            s += ((volatile float*)pl)[i];
            c += ((volatile float*)pc)[i];
        }
        #pragma unroll
        for (int o = 32; o > 0; o >>= 1) {
            s += __shfl_down(s, o, 64);
            c += __shfl_down(c, o, 64);
        }
        __shared__ float fs[TPB / 64], fc[TPB / 64];
        if ((t & 63) == 0) { fs[t >> 6] = s; fc[t >> 6] = c; }
        __syncthreads();
        if (t == 0) {
            float ts = fs[0] + fs[1] + fs[2] + fs[3];
            float tc = fc[0] + fc[1] + fc[2] + fc[3];
            out[0] = ts / fmaxf(tc, 1.f);
        }
    }
}

extern "C" void kernel_launch(void* const* d_in, const int* in_sizes, int n_in,
                              void* d_out, int out_size, void* d_ws, size_t ws_size,
                              hipStream_t stream) {
    const float* px = (const float*)d_in[0];
    const float* py = (const float*)d_in[1];
    const int2* tgt = (const int2*)d_in[2];
    float* out = (float*)d_out;

    float* pl = (float*)d_ws;
    float* pc = pl + NBLK;
    unsigned* ticket = (unsigned*)(pc + NBLK);

    hipMemsetAsync(ticket, 0, sizeof(unsigned), stream);
    bce_fused<<<dim3(NBLK), dim3(TPB), 0, stream>>>(px, py, tgt, pl, pc, ticket, out);
}

// Round 7
// 113.398 us; speedup vs baseline: 1.8573x; 1.8573x over previous
//
#include <hip/hip_runtime.h>

#define WDIM 1920
#define HDIM 1080
#define TPB 256
#define PPB 4                 // pairs per block
#define NBLK 2048             // 8192 / PPB
#define XF4 (PPB * WDIM / 4)  // 1920 float4s per block x-region
#define YF4 (PPB * HDIM / 4)  // 1080 float4s per block y-region
#define LN2 0.69314718056f

__device__ __forceinline__ float clog1m(float p) {
    return fmaxf(__log2f(1.f - p) * LN2, -100.f);
}
__device__ __forceinline__ float clogp(float p) {
    return fmaxf(__log2f(p) * LN2, -100.f);
}

__global__ __launch_bounds__(TPB) void bce_main(const float* __restrict__ px,
                                                const float* __restrict__ py,
                                                const int2* __restrict__ tgt,
                                                float* __restrict__ partial_loss,
                                                float* __restrict__ partial_cnt) {
    const int t = threadIdx.x;
    const int blk = blockIdx.x;
    const int p0 = blk * PPB;

    // Per-pair stream weights (vm * -ln2/L); block owns its 4 pairs.
    __shared__ float wx[PPB], wy[PPB];
    int cx = 0, cy = 0;
    float vm = 0.f;
    if (t < PPB) {
        int2 t2 = tgt[p0 + t];
        cx = min(max(t2.x, 0), WDIM - 1);
        cy = min(max(t2.y, 0), HDIM - 1);
        vm = (cx == 0 && cy == 0) ? 0.f : 1.f;
        wx[t] = vm * (-LN2 / WDIM);
        wy[t] = vm * (-LN2 / HDIM);
    }
    __syncthreads();

    float acc = 0.f, cnt = 0.f;
    // Target-element corrections: owning block, one pair per lane (t<4).
    // p can be 0/1 here -> keep clamps.
    if (t < PPB && vm != 0.f) {
        float pt = px[(size_t)(p0 + t) * WDIM + cx];
        float qt = py[(size_t)(p0 + t) * HDIM + cy];
        acc += (clog1m(pt) - clogp(pt)) * (1.f / WDIM)
             + (clog1m(qt) - clogp(qt)) * (1.f / HDIM);
        cnt = 1.f;
    }

    const float4* bx = (const float4*)px + (size_t)blk * XF4;
    const float4* by = (const float4*)py + (size_t)blk * YF4;
    const float4 z4 = make_float4(0.f, 0.f, 0.f, 0.f);

    // ---- x region: 1920 float4s, batched loads, predicated tail ----
    float4 vx[8];
    #pragma unroll
    for (int j = 0; j < 8; ++j) {
        int idx = t + j * TPB;
        vx[j] = (j < 7 || t < XF4 - 7 * TPB) ? bx[idx] : z4;   // pad -> q=1 -> log 0
    }
    #pragma unroll
    for (int j = 0; j < 8; ++j) {
        int idx = t + j * TPB;
        // clamp: padded tail idx would give pli=4 -> OOB shared read (R6 NaN bug)
        int pli = min(idx / 480, PPB - 1);
        float4 v = vx[j];
        // log-of-product-of-4: min (5.96e-8)^4 = 1.26e-29 (normal); per-element
        // log >= -16.6 so the -100 clamp can never bind on this path.
        float q = (1.f - v.x) * (1.f - v.y) * (1.f - v.z) * (1.f - v.w);
        acc += wx[pli] * __log2f(q);
    }

    // ---- y region: 1080 float4s ----
    float4 vy[5];
    #pragma unroll
    for (int j = 0; j < 5; ++j) {
        int idx = t + j * TPB;
        vy[j] = (j < 4 || t < YF4 - 4 * TPB) ? by[idx] : z4;
    }
    #pragma unroll
    for (int j = 0; j < 5; ++j) {
        int idx = t + j * TPB;
        int pli = min(idx / 270, PPB - 1);   // clamp: same OOB guard
        float4 v = vy[j];
        float q = (1.f - v.x) * (1.f - v.y) * (1.f - v.z) * (1.f - v.w);
        acc += wy[pli] * __log2f(q);
    }

    // block reduce (no atomics, no fences)
    #pragma unroll
    for (int o = 32; o > 0; o >>= 1) {
        acc += __shfl_down(acc, o, 64);
        cnt += __shfl_down(cnt, o, 64);
    }
    __shared__ float rs[TPB / 64], rc[TPB / 64];
    if ((t & 63) == 0) { rs[t >> 6] = acc; rc[t >> 6] = cnt; }
    __syncthreads();
    if (t == 0) {
        partial_loss[blk] = rs[0] + rs[1] + rs[2] + rs[3];
        partial_cnt[blk]  = rc[0] + rc[1] + rc[2] + rc[3];
    }
}

__global__ __launch_bounds__(TPB) void bce_final(const float* __restrict__ pl,
                                                 const float* __restrict__ pc,
                                                 int nblk, float* __restrict__ out) {
    const int t = threadIdx.x;
    float s = 0.f, c = 0.f;
    for (int i = t; i < nblk; i += TPB) { s += pl[i]; c += pc[i]; }
    #pragma unroll
    for (int o = 32; o > 0; o >>= 1) {
        s += __shfl_down(s, o, 64);
        c += __shfl_down(c, o, 64);
    }
    __shared__ float rs[TPB / 64], rc[TPB / 64];
    if ((t & 63) == 0) { rs[t >> 6] = s; rc[t >> 6] = c; }
    __syncthreads();
    if (t == 0) {
        float ts = rs[0] + rs[1] + rs[2] + rs[3];
        float tc = rc[0] + rc[1] + rc[2] + rc[3];
        out[0] = ts / fmaxf(tc, 1.f);
    }
}

extern "C" void kernel_launch(void* const* d_in, const int* in_sizes, int n_in,
                              void* d_out, int out_size, void* d_ws, size_t ws_size,
                              hipStream_t stream) {
    const float* px = (const float*)d_in[0];
    const float* py = (const float*)d_in[1];
    const int2* tgt = (const int2*)d_in[2];
    float* out = (float*)d_out;

    float* pl = (float*)d_ws;
    float* pc = pl + NBLK;

    bce_main<<<dim3(NBLK), dim3(TPB), 0, stream>>>(px, py, tgt, pl, pc);
    bce_final<<<1, TPB, 0, stream>>>(pl, pc, NBLK, out);
}